// Round 1
// baseline (163.017 us; speedup 1.0000x reference)
//
#include <hip/hip_runtime.h>
#include <hip/hip_bf16.h>

// Problem constants
#define B_  8
#define N_  512
#define C_  1024
#define H_  16
#define HD_ 64
#define M_  4096   // B*N

typedef float  f32x4  __attribute__((ext_vector_type(4)));
typedef __bf16 bf16x8 __attribute__((ext_vector_type(8)));
typedef unsigned short ushort_t;

__device__ __forceinline__ ushort_t f2bf(float f) {
  union { float f; unsigned int u; } un; un.f = f;
  unsigned int u = un.u;
  return (ushort_t)((u + 0x7fffu + ((u >> 16) & 1u)) >> 16);  // RNE
}

// async global->LDS, 16B per lane; lds pointer must be wave-uniform (lane*16 added by HW)
__device__ __forceinline__ void gload16(const void* g, void* l) {
  __builtin_amdgcn_global_load_lds((const __attribute__((address_space(1))) void*)g,
                                   (__attribute__((address_space(3))) void*)l, 16, 0, 0);
}

// ---------------------------------------------------------------------------
// Kernel 1: elementwise prep. One block per (b,n) row.
//  xb = bf16(x); kp = bf16(mu/bv); vp = bf16(8*mu/bv); bias = log(alpha) - 0.5*sum(mu^2/bv)
// ---------------------------------------------------------------------------
__global__ __launch_bounds__(256) void prep_kernel(
    const float* __restrict__ x, const float* __restrict__ mu,
    const float* __restrict__ logvar, const float* __restrict__ alpha,
    ushort_t* __restrict__ xb, ushort_t* __restrict__ kp, ushort_t* __restrict__ vp,
    float* __restrict__ biasv) {
  const int row = blockIdx.x;
  const int t   = threadIdx.x;
  const int base = row * C_ + t * 4;
  float4 xv = *(const float4*)(x + base);
  float4 mv = *(const float4*)(mu + base);
  float4 lv = *(const float4*)(logvar + base);
  float xa[4] = {xv.x, xv.y, xv.z, xv.w};
  float ma[4] = {mv.x, mv.y, mv.z, mv.w};
  float la[4] = {lv.x, lv.y, lv.z, lv.w};
  ushort4 xs, ks, vs;
  ushort_t* xsp = &xs.x; ushort_t* ksp = &ks.x; ushort_t* vsp = &vs.x;
  float l2 = 0.f;
#pragma unroll
  for (int i = 0; i < 4; ++i) {
    float bv  = __expf(la[i]) + 8.0f;   // exp(logvar) + sqrt(HD)
    float inv = 1.0f / bv;
    float kf  = ma[i] * inv;
    float vf  = 8.0f * ma[i] * inv;
    l2 += ma[i] * ma[i] * inv;
    xsp[i] = f2bf(xa[i]); ksp[i] = f2bf(kf); vsp[i] = f2bf(vf);
  }
  *(ushort4*)(xb + base) = xs;
  *(ushort4*)(kp + base) = ks;
  *(ushort4*)(vp + base) = vs;
  // block reduce l2 (fp32: magnitude ~57, must be accurate)
  l2 += __shfl_xor(l2, 1);  l2 += __shfl_xor(l2, 2);  l2 += __shfl_xor(l2, 4);
  l2 += __shfl_xor(l2, 8);  l2 += __shfl_xor(l2, 16); l2 += __shfl_xor(l2, 32);
  __shared__ float red[4];
  if ((t & 63) == 0) red[t >> 6] = l2;
  __syncthreads();
  if (t == 0) {
    float s = red[0] + red[1] + red[2] + red[3];
    biasv[row] = __logf(alpha[row]) - 0.5f * s;
  }
}

// ---------------------------------------------------------------------------
// Kernel 2: cast the 4 weight matrices to bf16 (packed wq|wk|wv|wp)
// ---------------------------------------------------------------------------
__global__ __launch_bounds__(256) void castw_kernel(
    const float* __restrict__ wq, const float* __restrict__ wk,
    const float* __restrict__ wv, const float* __restrict__ wp,
    ushort_t* __restrict__ dst) {
  int i = (blockIdx.x * 256 + threadIdx.x) * 4;   // 0 .. 4M-4
  int sel = i >> 20;
  int off = i & 0xFFFFF;
  const float* src = sel == 0 ? wq : sel == 1 ? wk : sel == 2 ? wv : wp;
  float4 v = *(const float4*)(src + off);
  ushort4 o;
  o.x = f2bf(v.x); o.y = f2bf(v.y); o.z = f2bf(v.z); o.w = f2bf(v.w);
  *(ushort4*)(dst + i) = o;
}

// ---------------------------------------------------------------------------
// GEMM core: C[m][n] = sum_k A[m][k] * W[n][k]   (both row-major, K=1024)
// 128x128 tile, BK=32, 256 threads (2x2 waves, 64x64 per wave).
// LDS chunk-major [chunk][row] in 16B units -> linear for global_load_lds,
// uniform bank spread on ds_read_b128 fragment reads.
// ---------------------------------------------------------------------------
__device__ __forceinline__ void gemm_tile(const ushort_t* __restrict__ Ag,
                                          const ushort_t* __restrict__ Wg,
                                          int m0, int n0, f32x4 acc[4][4],
                                          ushort_t* lds) {
  const int t = threadIdx.x;
  const int w = t >> 6, lane = t & 63;
  const int wm = w >> 1, wn = w & 1;
  const int chunk = lane >> 4, r15 = lane & 15;
  for (int kt = 0; kt < 32; ++kt) {
    const int k0 = kt * 32;
    {
      int s0 = t, s1 = t + 256;
      gload16(Ag + (size_t)(m0 + (s0 & 127)) * 1024 + k0 + (s0 >> 7) * 8,
              lds + (s0 & ~63) * 8);
      gload16(Ag + (size_t)(m0 + (s1 & 127)) * 1024 + k0 + (s1 >> 7) * 8,
              lds + (s1 & ~63) * 8);
      gload16(Wg + (size_t)(n0 + (s0 & 127)) * 1024 + k0 + (s0 >> 7) * 8,
              lds + 4096 + (s0 & ~63) * 8);
      gload16(Wg + (size_t)(n0 + (s1 & 127)) * 1024 + k0 + (s1 >> 7) * 8,
              lds + 4096 + (s1 & ~63) * 8);
    }
    __syncthreads();   // compiler drains vmcnt before s_barrier -> staged data visible
    bf16x8 af[4], bw[4];
#pragma unroll
    for (int mi = 0; mi < 4; ++mi)
      af[mi] = *(const bf16x8*)(lds + (chunk * 128 + wm * 64 + mi * 16 + r15) * 8);
#pragma unroll
    for (int ni = 0; ni < 4; ++ni)
      bw[ni] = *(const bf16x8*)(lds + 4096 + (chunk * 128 + wn * 64 + ni * 16 + r15) * 8);
#pragma unroll
    for (int mi = 0; mi < 4; ++mi)
#pragma unroll
      for (int ni = 0; ni < 4; ++ni)
        acc[mi][ni] = __builtin_amdgcn_mfma_f32_16x16x32_bf16(af[mi], bw[ni], acc[mi][ni], 0, 0, 0);
    __syncthreads();   // reads done before next stage overwrites
  }
}

// ---------------------------------------------------------------------------
// Kernel 3: Q/K/V projections. blockIdx.z selects which.
//  z=0: Q = xb @ wq^T  -> Qg   (B*N, C) bf16
//  z=1: K = kp @ wk^T  -> Kg   (B*N, C) bf16
//  z=2: V = vp @ wv^T  -> Vt   transposed per head: Vt[((b*16+h)*64+d)*512 + pos]
// ---------------------------------------------------------------------------
__global__ __launch_bounds__(256) void gemm_qkv_kernel(
    const ushort_t* __restrict__ xb, const ushort_t* __restrict__ kp,
    const ushort_t* __restrict__ vp, const ushort_t* __restrict__ wb,
    ushort_t* __restrict__ Qg, ushort_t* __restrict__ Kg, ushort_t* __restrict__ Vt) {
  __shared__ ushort_t lds[8192];
  const int z = blockIdx.z;
  const ushort_t* Ag = z == 0 ? xb : z == 1 ? kp : vp;
  const ushort_t* Wg = wb + (size_t)z * 1048576;
  const int m0 = blockIdx.x * 128, n0 = blockIdx.y * 128;
  f32x4 acc[4][4] = {};
  gemm_tile(Ag, Wg, m0, n0, acc, lds);
  const int t = threadIdx.x, w = t >> 6, lane = t & 63;
  const int wm = w >> 1, wn = w & 1;
  const int rbase = m0 + wm * 64 + (lane >> 4) * 4;
  const int cbase = n0 + wn * 64 + (lane & 15);
  if (z < 2) {
    ushort_t* Out = z == 0 ? Qg : Kg;
#pragma unroll
    for (int mi = 0; mi < 4; ++mi)
#pragma unroll
      for (int ni = 0; ni < 4; ++ni)
#pragma unroll
        for (int q = 0; q < 4; ++q)
          Out[(size_t)(rbase + mi * 16 + q) * 1024 + cbase + ni * 16] = f2bf(acc[mi][ni][q]);
  } else {
#pragma unroll
    for (int mi = 0; mi < 4; ++mi) {
      int m = rbase + mi * 16;
      int b = m >> 9, pos = m & 511;        // pos multiple of 4 -> 8B aligned store
#pragma unroll
      for (int ni = 0; ni < 4; ++ni) {
        int n = cbase + ni * 16;
        int h = n >> 6, d = n & 63;
        ushort4 o;
        o.x = f2bf(acc[mi][ni][0]); o.y = f2bf(acc[mi][ni][1]);
        o.z = f2bf(acc[mi][ni][2]); o.w = f2bf(acc[mi][ni][3]);
        *(ushort4*)(Vt + (size_t)((b * 16 + h) * 64 + d) * 512 + pos) = o;
      }
    }
  }
}

// ---------------------------------------------------------------------------
// Kernel 4: attention. Block = (b,h) x 64 query rows; 4 waves, 16 q-rows/wave.
// Full score row (512 keys) kept in registers: acc[32] f32x4 per lane.
// Register softmax via 16-lane shfl reduce; fp32 normalized probs -> d_out;
// P re-fragmented through 4KB/wave LDS for the PV MFMA (V pre-transposed).
// ---------------------------------------------------------------------------
__global__ __launch_bounds__(256, 2) void attn_kernel(
    const ushort_t* __restrict__ Qg, const ushort_t* __restrict__ Kg,
    const ushort_t* __restrict__ Vt, const float* __restrict__ biasv,
    float* __restrict__ attn_out, ushort_t* __restrict__ Og) {
  __shared__ ushort_t Qt[4096];   // 8KB : [chunk0..7][row0..63]   x 16B
  __shared__ ushort_t Kt[8192];   // 16KB: [chunk0..7][krow0..127] x 16B
  __shared__ ushort_t Pl[8192];   // 16KB: per-wave 2048 ushorts: [chunk0..15][row0..15] x 16B
  __shared__ ushort_t Vts[8192];  // 16KB: [chunk0..15][d0..63]    x 16B
  __shared__ float biasl[512];
  const int bh = blockIdx.x, qt = blockIdx.y;
  const int b = bh >> 4, h = bh & 15;
  const int t = threadIdx.x, w = t >> 6, lane = t & 63;
  const int hi = lane >> 4, r15 = lane & 15;

  { // stage Q tile + bias row
    int s0 = t, s1 = t + 256;
    gload16(Qg + (size_t)(b * 512 + qt * 64 + (s0 & 63)) * 1024 + h * 64 + (s0 >> 6) * 8,
            Qt + (s0 & ~63) * 8);
    gload16(Qg + (size_t)(b * 512 + qt * 64 + (s1 & 63)) * 1024 + h * 64 + (s1 >> 6) * 8,
            Qt + (s1 & ~63) * 8);
    float2 bv2 = *(const float2*)(biasv + b * 512 + t * 2);
    biasl[t * 2] = bv2.x; biasl[t * 2 + 1] = bv2.y;
  }

  f32x4 acc[32] = {};
  bf16x8 aq[2];

  // ---- S = Q K^T ----
#pragma unroll
  for (int kt = 0; kt < 4; ++kt) {
#pragma unroll
    for (int r = 0; r < 4; ++r) {
      int s = r * 256 + t;   // chunk = s>>7, krow = s&127
      gload16(Kg + (size_t)(b * 512 + kt * 128 + (s & 127)) * 1024 + h * 64 + (s >> 7) * 8,
              Kt + (s & ~63) * 8);
    }
    __syncthreads();
    if (kt == 0) {
#pragma unroll
      for (int ks = 0; ks < 2; ++ks)
        aq[ks] = *(const bf16x8*)(Qt + ((ks * 4 + hi) * 64 + w * 16 + r15) * 8);
    }
#pragma unroll
    for (int mf = 0; mf < 8; ++mf)
#pragma unroll
      for (int ks = 0; ks < 2; ++ks) {
        bf16x8 bk = *(const bf16x8*)(Kt + ((ks * 4 + hi) * 128 + mf * 16 + r15) * 8);
        acc[kt * 8 + mf] = __builtin_amdgcn_mfma_f32_16x16x32_bf16(aq[ks], bk, acc[kt * 8 + mf], 0, 0, 0);
      }
    __syncthreads();
  }

  // ---- bias + softmax (registers only; row r = w*16 + hi*4 + q, col = f*16 + r15) ----
  float mx[4] = {-1e30f, -1e30f, -1e30f, -1e30f};
#pragma unroll
  for (int f = 0; f < 32; ++f) {
    float bv = biasl[f * 16 + r15];
#pragma unroll
    for (int q = 0; q < 4; ++q) {
      acc[f][q] += bv;
      mx[q] = fmaxf(mx[q], acc[f][q]);
    }
  }
#pragma unroll
  for (int q = 0; q < 4; ++q) {
    mx[q] = fmaxf(mx[q], __shfl_xor(mx[q], 1));
    mx[q] = fmaxf(mx[q], __shfl_xor(mx[q], 2));
    mx[q] = fmaxf(mx[q], __shfl_xor(mx[q], 4));
    mx[q] = fmaxf(mx[q], __shfl_xor(mx[q], 8));
  }
  float sm[4] = {0.f, 0.f, 0.f, 0.f};
#pragma unroll
  for (int f = 0; f < 32; ++f)
#pragma unroll
    for (int q = 0; q < 4; ++q) {
      float p = __expf(acc[f][q] - mx[q]);
      acc[f][q] = p;
      sm[q] += p;
    }
#pragma unroll
  for (int q = 0; q < 4; ++q) {
    sm[q] += __shfl_xor(sm[q], 1);
    sm[q] += __shfl_xor(sm[q], 2);
    sm[q] += __shfl_xor(sm[q], 4);
    sm[q] += __shfl_xor(sm[q], 8);
    sm[q] = 1.0f / sm[q];
  }
  float* ao = attn_out + ((size_t)bh * 512 + qt * 64 + w * 16 + hi * 4) * 512 + r15;
#pragma unroll
  for (int f = 0; f < 32; ++f)
#pragma unroll
    for (int q = 0; q < 4; ++q) {
      float p = acc[f][q] * sm[q];
      acc[f][q] = p;                         // keep normalized P for PV
      ao[(size_t)q * 512 + f * 16] = p;      // fp32 attn output, 64B/16-lane segments
    }

  // ---- O = P V ----
  f32x4 oacc[4] = {};
#pragma unroll
  for (int kt = 0; kt < 4; ++kt) {
    // write this kt's P slab (cols kt*128..+128) as bf16, chunk-major per wave
#pragma unroll
    for (int fl = 0; fl < 8; ++fl) {
      int f = kt * 8 + fl;
      int chunkp = fl * 2 + (r15 >> 3);
#pragma unroll
      for (int q = 0; q < 4; ++q)
        Pl[w * 2048 + (chunkp * 16 + hi * 4 + q) * 8 + (lane & 7)] = f2bf(acc[f][q]);
    }
    // stage V^T tile: [chunk0..15][d0..63], chunk = s>>6? no: chunk = s>>6 has 16 values
#pragma unroll
    for (int r = 0; r < 4; ++r) {
      int s = r * 256 + t;   // chunk = s>>6 (0..15), d = s&63
      gload16(Vt + (size_t)(bh * 64 + (s & 63)) * 512 + kt * 128 + (s >> 6) * 8,
              Vts + (s & ~63) * 8);
    }
    __syncthreads();
#pragma unroll
    for (int ks = 0; ks < 4; ++ks) {
      bf16x8 pa = *(const bf16x8*)(Pl + w * 2048 + ((ks * 4 + hi) * 16 + r15) * 8);
#pragma unroll
      for (int df = 0; df < 4; ++df) {
        bf16x8 vb = *(const bf16x8*)(Vts + ((ks * 4 + hi) * 64 + df * 16 + r15) * 8);
        oacc[df] = __builtin_amdgcn_mfma_f32_16x16x32_bf16(pa, vb, oacc[df], 0, 0, 0);
      }
    }
    __syncthreads();
  }
  // write O (bf16), row = b*512 + qt*64 + w*16 + hi*4 + q, col = h*64 + df*16 + r15
  size_t obase = (size_t)(b * 512 + qt * 64 + w * 16 + hi * 4) * 1024 + h * 64 + r15;
#pragma unroll
  for (int df = 0; df < 4; ++df)
#pragma unroll
    for (int q = 0; q < 4; ++q)
      Og[obase + (size_t)q * 1024 + df * 16] = f2bf(oacc[df][q]);
}

// ---------------------------------------------------------------------------
// Kernel 5: out = O @ wp^T + b_p  (fp32 output)
// ---------------------------------------------------------------------------
__global__ __launch_bounds__(256) void gemm_out_kernel(
    const ushort_t* __restrict__ Og, const ushort_t* __restrict__ wb,
    const float* __restrict__ bp, float* __restrict__ out) {
  __shared__ ushort_t lds[8192];
  const int m0 = blockIdx.x * 128, n0 = blockIdx.y * 128;
  f32x4 acc[4][4] = {};
  gemm_tile(Og, wb + 3 * 1048576, m0, n0, acc, lds);
  const int t = threadIdx.x, w = t >> 6, lane = t & 63;
  const int wm = w >> 1, wn = w & 1;
  const int rbase = m0 + wm * 64 + (lane >> 4) * 4;
  const int cbase = n0 + wn * 64 + (lane & 15);
#pragma unroll
  for (int mi = 0; mi < 4; ++mi)
#pragma unroll
    for (int ni = 0; ni < 4; ++ni) {
      float bias = bp[cbase + ni * 16];
#pragma unroll
      for (int q = 0; q < 4; ++q)
        out[(size_t)(rbase + mi * 16 + q) * 1024 + cbase + ni * 16] = acc[mi][ni][q] + bias;
    }
}

// ---------------------------------------------------------------------------
// Launch. Workspace layout (bytes):
//   0        xb (8MB)  -> reused as Og after QKV GEMMs complete
//   8MB      kp (8MB)
//   16MB     vp (8MB)
//   24MB     Qg (8MB)
//   32MB     Kg (8MB)
//   40MB     Vt (8MB, per-head transposed V)
//   48MB     wb (8MB, bf16 wq|wk|wv|wp)
//   56MB     biasv (16KB)
// Total ~58.7MB required.
// ---------------------------------------------------------------------------
extern "C" void kernel_launch(void* const* d_in, const int* in_sizes, int n_in,
                              void* d_out, int out_size, void* d_ws, size_t ws_size,
                              hipStream_t stream) {
  const float* x      = (const float*)d_in[0];
  const float* mu     = (const float*)d_in[1];
  const float* logvar = (const float*)d_in[2];
  const float* alpha  = (const float*)d_in[3];
  // d_in[4] = pi, d_in[5] = z : unused by the reference
  const float* wq = (const float*)d_in[6];
  const float* wk = (const float*)d_in[7];
  const float* wv = (const float*)d_in[8];
  const float* wp = (const float*)d_in[9];
  const float* bp = (const float*)d_in[10];

  float* out      = (float*)d_out;
  float* attn_out = out + (size_t)M_ * C_;   // second tuple element, fp32

  char* ws = (char*)d_ws;
  ushort_t* xb    = (ushort_t*)(ws);
  ushort_t* kp    = (ushort_t*)(ws + (size_t)8  * 1048576);
  ushort_t* vp    = (ushort_t*)(ws + (size_t)16 * 1048576);
  ushort_t* Qg    = (ushort_t*)(ws + (size_t)24 * 1048576);
  ushort_t* Kg    = (ushort_t*)(ws + (size_t)32 * 1048576);
  ushort_t* Vt    = (ushort_t*)(ws + (size_t)40 * 1048576);
  ushort_t* wb    = (ushort_t*)(ws + (size_t)48 * 1048576);
  float*    biasv = (float*)   (ws + (size_t)56 * 1048576);
  ushort_t* Og    = xb;   // xb dead after QKV GEMMs; attn runs strictly after

  castw_kernel<<<4096, 256, 0, stream>>>(wq, wk, wv, wp, wb);
  prep_kernel<<<4096, 256, 0, stream>>>(x, mu, logvar, alpha, xb, kp, vp, biasv);
  gemm_qkv_kernel<<<dim3(32, 8, 3), 256, 0, stream>>>(xb, kp, vp, wb, Qg, Kg, Vt);
  attn_kernel<<<dim3(128, 8), 256, 0, stream>>>(Qg, Kg, Vt, biasv, attn_out, Og);
  gemm_out_kernel<<<dim3(32, 8), 256, 0, stream>>>(Og, wb, bp, out);
}

// Round 3
// 140.474 us; speedup vs baseline: 1.1605x; 1.1605x over previous
//
#include <hip/hip_runtime.h>
#include <hip/hip_bf16.h>

// Problem constants
#define B_  8
#define N_  512
#define C_  1024
#define H_  16
#define HD_ 64
#define M_  4096   // B*N

typedef float  f32x4  __attribute__((ext_vector_type(4)));
typedef __bf16 bf16x8 __attribute__((ext_vector_type(8)));
typedef unsigned short ushort_t;

__device__ __forceinline__ ushort_t f2bf(float f) {
  union { float f; unsigned int u; } un; un.f = f;
  unsigned int u = un.u;
  return (ushort_t)((u + 0x7fffu + ((u >> 16) & 1u)) >> 16);  // RNE
}

// async global->LDS, 16B per lane; lds pointer must be wave-uniform (lane*16 added by HW)
__device__ __forceinline__ void gload16(const void* g, void* l) {
  __builtin_amdgcn_global_load_lds((const __attribute__((address_space(1))) void*)g,
                                   (__attribute__((address_space(3))) void*)l, 16, 0, 0);
}
#define SBAR()  __builtin_amdgcn_s_barrier()
#define SCHED() __builtin_amdgcn_sched_barrier(0)
#define VMCNT4() asm volatile("s_waitcnt vmcnt(4)" ::: "memory")
#define VMCNT0() asm volatile("s_waitcnt vmcnt(0)" ::: "memory")

// ---------------------------------------------------------------------------
// Kernel 1: fused elementwise prep (blocks 0..4095) + weight cast (4096..8191).
//  xb = bf16(x); kp = bf16(mu/bv); vp = bf16(8*mu/bv); bias = log(alpha)-0.5*sum(mu^2/bv)
//  wb = bf16(wq|wk|wv|wp)
// ---------------------------------------------------------------------------
__global__ __launch_bounds__(256) void prep_kernel(
    const float* __restrict__ x, const float* __restrict__ mu,
    const float* __restrict__ logvar, const float* __restrict__ alpha,
    const float* __restrict__ wq, const float* __restrict__ wk,
    const float* __restrict__ wv, const float* __restrict__ wp,
    ushort_t* __restrict__ xb, ushort_t* __restrict__ kp, ushort_t* __restrict__ vp,
    float* __restrict__ biasv, ushort_t* __restrict__ wb) {
  const int t = threadIdx.x;
  if (blockIdx.x >= 4096) {   // weight cast
    int i = ((blockIdx.x - 4096) * 256 + t) * 4;
    int sel = i >> 20;
    int off = i & 0xFFFFF;
    const float* src = sel == 0 ? wq : sel == 1 ? wk : sel == 2 ? wv : wp;
    float4 v = *(const float4*)(src + off);
    ushort4 o;
    o.x = f2bf(v.x); o.y = f2bf(v.y); o.z = f2bf(v.z); o.w = f2bf(v.w);
    *(ushort4*)(wb + i) = o;
    return;
  }
  const int row = blockIdx.x;
  const int base = row * C_ + t * 4;
  float4 xv = *(const float4*)(x + base);
  float4 mv = *(const float4*)(mu + base);
  float4 lv = *(const float4*)(logvar + base);
  float xa[4] = {xv.x, xv.y, xv.z, xv.w};
  float ma[4] = {mv.x, mv.y, mv.z, mv.w};
  float la[4] = {lv.x, lv.y, lv.z, lv.w};
  ushort4 xs, ks, vs;
  ushort_t* xsp = &xs.x; ushort_t* ksp = &ks.x; ushort_t* vsp = &vs.x;
  float l2 = 0.f;
#pragma unroll
  for (int i = 0; i < 4; ++i) {
    float bv  = __expf(la[i]) + 8.0f;   // exp(logvar) + sqrt(HD)
    float inv = 1.0f / bv;
    float kf  = ma[i] * inv;
    float vf  = 8.0f * ma[i] * inv;
    l2 += ma[i] * ma[i] * inv;
    xsp[i] = f2bf(xa[i]); ksp[i] = f2bf(kf); vsp[i] = f2bf(vf);
  }
  *(ushort4*)(xb + base) = xs;
  *(ushort4*)(kp + base) = ks;
  *(ushort4*)(vp + base) = vs;
  l2 += __shfl_xor(l2, 1);  l2 += __shfl_xor(l2, 2);  l2 += __shfl_xor(l2, 4);
  l2 += __shfl_xor(l2, 8);  l2 += __shfl_xor(l2, 16); l2 += __shfl_xor(l2, 32);
  __shared__ float red[4];
  if ((t & 63) == 0) red[t >> 6] = l2;
  __syncthreads();
  if (t == 0) {
    float s = red[0] + red[1] + red[2] + red[3];
    biasv[row] = __logf(alpha[row]) - 0.5f * s;
  }
}

// ---------------------------------------------------------------------------
// GEMM core, 2-phase double-buffered (T3 minimum recipe):
//   C[m][n] = sum_k A[m][k]*W[n][k], K=1024, 128x128 tile, BK=32, 256 thr.
// LDS: bufA[2][4096] | bufB[2][4096] ushorts (32KB). Chunk-major [chunk][row]
// 16B units -> linear dest for global_load_lds, uniform bank spread on reads.
// Raw s_barrier + counted vmcnt(4): next tile's 4 loads stay in flight.
// ---------------------------------------------------------------------------
__device__ __forceinline__ void gemm_tile_db(const ushort_t* __restrict__ Ag,
                                             const ushort_t* __restrict__ Wg,
                                             int m0, int n0, f32x4 acc[4][4],
                                             ushort_t* lds) {
  const int t = threadIdx.x;
  const int w = t >> 6, lane = t & 63;
  const int wm = w >> 1, wn = w & 1;
  const int chunk = lane >> 4, r15 = lane & 15;
  const int s0 = t, s1 = t + 256;

#define STAGE_AB(kt, buf)                                                         \
  do {                                                                            \
    const int k0 = (kt) * 32;                                                     \
    gload16(Ag + (size_t)(m0 + (s0 & 127)) * 1024 + k0 + (s0 >> 7) * 8,           \
            lds + (buf) * 4096 + (s0 & ~63) * 8);                                 \
    gload16(Ag + (size_t)(m0 + (s1 & 127)) * 1024 + k0 + (s1 >> 7) * 8,           \
            lds + (buf) * 4096 + (s1 & ~63) * 8);                                 \
    gload16(Wg + (size_t)(n0 + (s0 & 127)) * 1024 + k0 + (s0 >> 7) * 8,           \
            lds + 8192 + (buf) * 4096 + (s0 & ~63) * 8);                          \
    gload16(Wg + (size_t)(n0 + (s1 & 127)) * 1024 + k0 + (s1 >> 7) * 8,           \
            lds + 8192 + (buf) * 4096 + (s1 & ~63) * 8);                          \
  } while (0)

  STAGE_AB(0, 0);
  int cur = 0;
  for (int kt = 0; kt < 32; ++kt) {
    if (kt < 31) { STAGE_AB(kt + 1, cur ^ 1); VMCNT4(); }
    else         { VMCNT0(); }
    SBAR();   // everyone's tile-kt loads landed
    SCHED();
    bf16x8 af[4], bw[4];
#pragma unroll
    for (int mi = 0; mi < 4; ++mi)
      af[mi] = *(const bf16x8*)(lds + cur * 4096 + (chunk * 128 + wm * 64 + mi * 16 + r15) * 8);
#pragma unroll
    for (int ni = 0; ni < 4; ++ni)
      bw[ni] = *(const bf16x8*)(lds + 8192 + cur * 4096 + (chunk * 128 + wn * 64 + ni * 16 + r15) * 8);
#pragma unroll
    for (int mi = 0; mi < 4; ++mi)
#pragma unroll
      for (int ni = 0; ni < 4; ++ni)
        acc[mi][ni] = __builtin_amdgcn_mfma_f32_16x16x32_bf16(af[mi], bw[ni], acc[mi][ni], 0, 0, 0);
    SCHED();
    SBAR();   // reads of buf[cur] done before next iter stages into it
    SCHED();
    cur ^= 1;
  }
#undef STAGE_AB
}

// ---------------------------------------------------------------------------
// Kernel 2: Q/K/V projections. blockIdx.z selects which.
//  z=0: Q = xb@wq^T -> Qg ; z=1: K = kp@wk^T -> Kg
//  z=2: V = vp@wv^T -> Vt per-head transposed: Vt[((b*16+h)*64+d)*512 + pos]
// ---------------------------------------------------------------------------
__global__ __launch_bounds__(256) void gemm_qkv_kernel(
    const ushort_t* __restrict__ xb, const ushort_t* __restrict__ kp,
    const ushort_t* __restrict__ vp, const ushort_t* __restrict__ wb,
    ushort_t* __restrict__ Qg, ushort_t* __restrict__ Kg, ushort_t* __restrict__ Vt) {
  __shared__ ushort_t lds[16384];
  const int z = blockIdx.z;
  const ushort_t* Ag = z == 0 ? xb : z == 1 ? kp : vp;
  const ushort_t* Wg = wb + (size_t)z * 1048576;
  const int m0 = blockIdx.x * 128, n0 = blockIdx.y * 128;
  f32x4 acc[4][4] = {};
  gemm_tile_db(Ag, Wg, m0, n0, acc, lds);
  const int t = threadIdx.x, w = t >> 6, lane = t & 63;
  const int wm = w >> 1, wn = w & 1;
  const int rbase = m0 + wm * 64 + (lane >> 4) * 4;
  const int cbase = n0 + wn * 64 + (lane & 15);
  if (z < 2) {
    ushort_t* Out = z == 0 ? Qg : Kg;
#pragma unroll
    for (int mi = 0; mi < 4; ++mi)
#pragma unroll
      for (int ni = 0; ni < 4; ++ni)
#pragma unroll
        for (int q = 0; q < 4; ++q)
          Out[(size_t)(rbase + mi * 16 + q) * 1024 + cbase + ni * 16] = f2bf(acc[mi][ni][q]);
  } else {
#pragma unroll
    for (int mi = 0; mi < 4; ++mi) {
      int m = rbase + mi * 16;
      int b = m >> 9, pos = m & 511;        // pos multiple of 4 -> 8B aligned store
#pragma unroll
      for (int ni = 0; ni < 4; ++ni) {
        int n = cbase + ni * 16;
        int h = n >> 6, d = n & 63;
        ushort4 o;
        o.x = f2bf(acc[mi][ni][0]); o.y = f2bf(acc[mi][ni][1]);
        o.z = f2bf(acc[mi][ni][2]); o.w = f2bf(acc[mi][ni][3]);
        *(ushort4*)(Vt + (size_t)((b * 16 + h) * 64 + d) * 512 + pos) = o;
      }
    }
  }
}

// ---------------------------------------------------------------------------
// Kernel 3: attention. Block = (b,h) x 64 q-rows; 4 waves, 16 q-rows/wave.
// Full 512-key score row in registers (acc[32] f32x4/lane); register softmax
// via 16-lane shfl; K and V share one 32KB LDS double-buffer (K dead after
// QK^T); V tile 0 prefetched under the softmax VALU phase; 134MB fp32 attn
// store deferred to the end so counted vmcnt waits see only the 4 V-loads.
// ---------------------------------------------------------------------------
__global__ __launch_bounds__(256, 2) void attn_kernel(
    const ushort_t* __restrict__ Qg, const ushort_t* __restrict__ Kg,
    const ushort_t* __restrict__ Vt, const float* __restrict__ biasv,
    float* __restrict__ attn_out, ushort_t* __restrict__ Og) {
  __shared__ ushort_t Qt[4096];     // 8KB : [chunk0..7][qrow0..63] x 16B
  __shared__ ushort_t KV[16384];    // 32KB: double buffer, 8192 ushorts each
  __shared__ ushort_t Pl[8192];     // 16KB: per-wave 2048 ushorts
  __shared__ float biasl[512];
  const int bh = blockIdx.x, qt = blockIdx.y;
  const int b = bh >> 4, h = bh & 15;
  const int t = threadIdx.x, w = t >> 6, lane = t & 63;
  const int hi = lane >> 4, r15 = lane & 15;

  // bias row first (its VGPR load's auto-waitcnt must not drain the stages)
  {
    float2 bv2 = *(const float2*)(biasv + b * 512 + t * 2);
    biasl[t * 2] = bv2.x; biasl[t * 2 + 1] = bv2.y;
  }
  { // stage Q tile
    int s0 = t, s1 = t + 256;
    gload16(Qg + (size_t)(b * 512 + qt * 64 + (s0 & 63)) * 1024 + h * 64 + (s0 >> 6) * 8,
            Qt + (s0 & ~63) * 8);
    gload16(Qg + (size_t)(b * 512 + qt * 64 + (s1 & 63)) * 1024 + h * 64 + (s1 >> 6) * 8,
            Qt + (s1 & ~63) * 8);
  }

#define STAGE_K(kt, buf)                                                               \
  do {                                                                                 \
    _Pragma("unroll")                                                                  \
    for (int r = 0; r < 4; ++r) {                                                      \
      int s = r * 256 + t; /* chunk=s>>7 (0..7), krow=s&127 */                         \
      gload16(Kg + (size_t)(b * 512 + (kt) * 128 + (s & 127)) * 1024 + h * 64 + (s >> 7) * 8, \
              KV + (buf) * 8192 + (s & ~63) * 8);                                      \
    }                                                                                  \
  } while (0)
#define STAGE_V(kt, buf)                                                               \
  do {                                                                                 \
    _Pragma("unroll")                                                                  \
    for (int r = 0; r < 4; ++r) {                                                      \
      int s = r * 256 + t; /* chunk=s>>6 (0..15), d=s&63 */                            \
      gload16(Vt + (size_t)(bh * 64 + (s & 63)) * 512 + (kt) * 128 + (s >> 6) * 8,     \
              KV + (buf) * 8192 + (s & ~63) * 8);                                      \
    }                                                                                  \
  } while (0)

  STAGE_K(0, 0);
  f32x4 acc[32] = {};
  bf16x8 aq[2];
  int cur = 0;

  // ---- S = Q K^T (2-phase pipelined; last iter prefetches V0) ----
#pragma unroll
  for (int kt = 0; kt < 4; ++kt) {
    if (kt < 3) STAGE_K(kt + 1, cur ^ 1);
    else        STAGE_V(0, cur ^ 1);        // V0 flies through the softmax phase
    VMCNT4();
    SBAR();
    SCHED();
    if (kt == 0) {
#pragma unroll
      for (int ks = 0; ks < 2; ++ks)
        aq[ks] = *(const bf16x8*)(Qt + ((ks * 4 + hi) * 64 + w * 16 + r15) * 8);
    }
    __builtin_amdgcn_s_setprio(1);
#pragma unroll
    for (int mf = 0; mf < 8; ++mf)
#pragma unroll
      for (int ks = 0; ks < 2; ++ks) {
        bf16x8 bk = *(const bf16x8*)(KV + cur * 8192 + ((ks * 4 + hi) * 128 + mf * 16 + r15) * 8);
        acc[kt * 8 + mf] = __builtin_amdgcn_mfma_f32_16x16x32_bf16(aq[ks], bk, acc[kt * 8 + mf], 0, 0, 0);
      }
    __builtin_amdgcn_s_setprio(0);
    SCHED();
    SBAR();
    SCHED();
    cur ^= 1;
  }

  // ---- bias + softmax (registers; row = w*16+hi*4+q, col = f*16+r15) ----
  float mx[4] = {-1e30f, -1e30f, -1e30f, -1e30f};
#pragma unroll
  for (int f = 0; f < 32; ++f) {
    float bv = biasl[f * 16 + r15];
#pragma unroll
    for (int q = 0; q < 4; ++q) {
      acc[f][q] += bv;
      mx[q] = fmaxf(mx[q], acc[f][q]);
    }
  }
#pragma unroll
  for (int q = 0; q < 4; ++q) {
    mx[q] = fmaxf(mx[q], __shfl_xor(mx[q], 1));
    mx[q] = fmaxf(mx[q], __shfl_xor(mx[q], 2));
    mx[q] = fmaxf(mx[q], __shfl_xor(mx[q], 4));
    mx[q] = fmaxf(mx[q], __shfl_xor(mx[q], 8));
  }
  float sm[4] = {0.f, 0.f, 0.f, 0.f};
#pragma unroll
  for (int f = 0; f < 32; ++f)
#pragma unroll
    for (int q = 0; q < 4; ++q) {
      float p = __expf(acc[f][q] - mx[q]);
      acc[f][q] = p;
      sm[q] += p;
    }
#pragma unroll
  for (int q = 0; q < 4; ++q) {
    sm[q] += __shfl_xor(sm[q], 1);
    sm[q] += __shfl_xor(sm[q], 2);
    sm[q] += __shfl_xor(sm[q], 4);
    sm[q] += __shfl_xor(sm[q], 8);
    sm[q] = 1.0f / sm[q];
  }
#pragma unroll
  for (int f = 0; f < 32; ++f)
#pragma unroll
    for (int q = 0; q < 4; ++q)
      acc[f][q] *= sm[q];                   // normalized P, kept for PV + final store

  // ---- O = P V (2-phase; P slab is per-wave private -> no barrier for it) ----
  f32x4 oacc[4] = {};
#pragma unroll
  for (int kt = 0; kt < 4; ++kt) {
    if (kt < 3) STAGE_V(kt + 1, cur ^ 1);
    // write this kt's P slab (cols kt*128..+128) as bf16, chunk-major per wave
#pragma unroll
    for (int fl = 0; fl < 8; ++fl) {
      int f = kt * 8 + fl;
      int chunkp = fl * 2 + (r15 >> 3);
#pragma unroll
      for (int q = 0; q < 4; ++q)
        Pl[w * 2048 + (chunkp * 16 + hi * 4 + q) * 8 + (lane & 7)] = f2bf(acc[f][q]);
    }
    if (kt < 3) VMCNT4(); else VMCNT0();
    SBAR();
    SCHED();
    __builtin_amdgcn_s_setprio(1);
#pragma unroll
    for (int ks = 0; ks < 4; ++ks) {
      bf16x8 pa = *(const bf16x8*)(Pl + w * 2048 + ((ks * 4 + hi) * 16 + r15) * 8);
#pragma unroll
      for (int df = 0; df < 4; ++df) {
        bf16x8 vb = *(const bf16x8*)(KV + cur * 8192 + ((ks * 4 + hi) * 64 + df * 16 + r15) * 8);
        oacc[df] = __builtin_amdgcn_mfma_f32_16x16x32_bf16(pa, vb, oacc[df], 0, 0, 0);
      }
    }
    __builtin_amdgcn_s_setprio(0);
    SCHED();
    SBAR();
    SCHED();
    cur ^= 1;
  }

  // ---- deferred stores: attn (fp32, mandatory 134MB) then O (bf16) ----
  float* ao = attn_out + ((size_t)bh * 512 + qt * 64 + w * 16 + hi * 4) * 512 + r15;
#pragma unroll
  for (int f = 0; f < 32; ++f)
#pragma unroll
    for (int q = 0; q < 4; ++q)
      ao[(size_t)q * 512 + f * 16] = acc[f][q];

  size_t obase = (size_t)(b * 512 + qt * 64 + w * 16 + hi * 4) * 1024 + h * 64 + r15;
#pragma unroll
  for (int df = 0; df < 4; ++df)
#pragma unroll
    for (int q = 0; q < 4; ++q)
      Og[obase + (size_t)q * 1024 + df * 16] = f2bf(oacc[df][q]);
#undef STAGE_K
#undef STAGE_V
}

// ---------------------------------------------------------------------------
// Kernel 4: out = O @ wp^T + b_p  (fp32 output)
// ---------------------------------------------------------------------------
__global__ __launch_bounds__(256) void gemm_out_kernel(
    const ushort_t* __restrict__ Og, const ushort_t* __restrict__ wb,
    const float* __restrict__ bp, float* __restrict__ out) {
  __shared__ ushort_t lds[16384];
  const int m0 = blockIdx.x * 128, n0 = blockIdx.y * 128;
  f32x4 acc[4][4] = {};
  gemm_tile_db(Og, wb + 3 * 1048576, m0, n0, acc, lds);
  const int t = threadIdx.x, w = t >> 6, lane = t & 63;
  const int wm = w >> 1, wn = w & 1;
  const int rbase = m0 + wm * 64 + (lane >> 4) * 4;
  const int cbase = n0 + wn * 64 + (lane & 15);
#pragma unroll
  for (int mi = 0; mi < 4; ++mi)
#pragma unroll
    for (int ni = 0; ni < 4; ++ni) {
      float bias = bp[cbase + ni * 16];
#pragma unroll
      for (int q = 0; q < 4; ++q)
        out[(size_t)(rbase + mi * 16 + q) * 1024 + cbase + ni * 16] = acc[mi][ni][q] + bias;
    }
}

// ---------------------------------------------------------------------------
// Launch. Workspace layout (bytes):
//   0     xb (8MB) -> reused as Og after QKV   24MB  Qg (8MB)   48MB wb (8MB)
//   8MB   kp (8MB)                             32MB  Kg (8MB)   56MB biasv(16KB)
//   16MB  vp (8MB)                             40MB  Vt (8MB)
// ---------------------------------------------------------------------------
extern "C" void kernel_launch(void* const* d_in, const int* in_sizes, int n_in,
                              void* d_out, int out_size, void* d_ws, size_t ws_size,
                              hipStream_t stream) {
  const float* x      = (const float*)d_in[0];
  const float* mu     = (const float*)d_in[1];
  const float* logvar = (const float*)d_in[2];
  const float* alpha  = (const float*)d_in[3];
  // d_in[4]=pi, d_in[5]=z : unused by the reference
  const float* wq = (const float*)d_in[6];
  const float* wk = (const float*)d_in[7];
  const float* wv = (const float*)d_in[8];
  const float* wp = (const float*)d_in[9];
  const float* bp = (const float*)d_in[10];

  float* out      = (float*)d_out;
  float* attn_out = out + (size_t)M_ * C_;   // second tuple element, fp32

  char* ws = (char*)d_ws;
  ushort_t* xb    = (ushort_t*)(ws);
  ushort_t* kp    = (ushort_t*)(ws + (size_t)8  * 1048576);
  ushort_t* vp    = (ushort_t*)(ws + (size_t)16 * 1048576);
  ushort_t* Qg    = (ushort_t*)(ws + (size_t)24 * 1048576);
  ushort_t* Kg    = (ushort_t*)(ws + (size_t)32 * 1048576);
  ushort_t* Vt    = (ushort_t*)(ws + (size_t)40 * 1048576);
  ushort_t* wb    = (ushort_t*)(ws + (size_t)48 * 1048576);
  float*    biasv = (float*)   (ws + (size_t)56 * 1048576);
  ushort_t* Og    = xb;   // xb dead after QKV GEMMs; attn runs strictly after

  prep_kernel<<<8192, 256, 0, stream>>>(x, mu, logvar, alpha, wq, wk, wv, wp,
                                        xb, kp, vp, biasv, wb);
  gemm_qkv_kernel<<<dim3(32, 8, 3), 256, 0, stream>>>(xb, kp, vp, wb, Qg, Kg, Vt);
  attn_kernel<<<dim3(128, 8), 256, 0, stream>>>(Qg, Kg, Vt, biasv, attn_out, Og);
  gemm_out_kernel<<<dim3(32, 8), 256, 0, stream>>>(Og, wb, bp, out);
}

// Round 5
// 137.386 us; speedup vs baseline: 1.1866x; 1.0225x over previous
//
#include <hip/hip_runtime.h>
#include <hip/hip_bf16.h>

// Problem constants
#define B_  8
#define N_  512
#define C_  1024
#define H_  16
#define HD_ 64
#define M_  4096   // B*N

typedef float  f32x4  __attribute__((ext_vector_type(4)));
typedef __bf16 bf16x8 __attribute__((ext_vector_type(8)));
typedef unsigned short ushort_t;

__device__ __forceinline__ ushort_t f2bf(float f) {
  union { float f; unsigned int u; } un; un.f = f;
  unsigned int u = un.u;
  return (ushort_t)((u + 0x7fffu + ((u >> 16) & 1u)) >> 16);  // RNE
}

// async global->LDS, 16B per lane; lds pointer must be wave-uniform (lane*16 added by HW)
__device__ __forceinline__ void gload16(const void* g, void* l) {
  __builtin_amdgcn_global_load_lds((const __attribute__((address_space(1))) void*)g,
                                   (__attribute__((address_space(3))) void*)l, 16, 0, 0);
}
#define SBAR()  __builtin_amdgcn_s_barrier()
#define SCHED() __builtin_amdgcn_sched_barrier(0)
#define VMCNT8() asm volatile("s_waitcnt vmcnt(8)" ::: "memory")
#define VMCNT4() asm volatile("s_waitcnt vmcnt(4)" ::: "memory")
#define VMCNT0() asm volatile("s_waitcnt vmcnt(0)" ::: "memory")

// ---------------------------------------------------------------------------
// Kernel 1: fused elementwise prep (blocks 0..4095) + weight cast (4096..8191).
//  xb = bf16(x); kp = bf16(mu/bv); vp = bf16(8*mu/bv); bias = log(alpha)-0.5*sum(mu^2/bv)
//  wb = bf16(wq|wk|wv|wp)
// ---------------------------------------------------------------------------
__global__ __launch_bounds__(256) void prep_kernel(
    const float* __restrict__ x, const float* __restrict__ mu,
    const float* __restrict__ logvar, const float* __restrict__ alpha,
    const float* __restrict__ wq, const float* __restrict__ wk,
    const float* __restrict__ wv, const float* __restrict__ wp,
    ushort_t* __restrict__ xb, ushort_t* __restrict__ kp, ushort_t* __restrict__ vp,
    float* __restrict__ biasv, ushort_t* __restrict__ wb) {
  const int t = threadIdx.x;
  if (blockIdx.x >= 4096) {   // weight cast
    int i = ((blockIdx.x - 4096) * 256 + t) * 4;
    int sel = i >> 20;
    int off = i & 0xFFFFF;
    const float* src = sel == 0 ? wq : sel == 1 ? wk : sel == 2 ? wv : wp;
    float4 v = *(const float4*)(src + off);
    ushort4 o;
    o.x = f2bf(v.x); o.y = f2bf(v.y); o.z = f2bf(v.z); o.w = f2bf(v.w);
    *(ushort4*)(wb + i) = o;
    return;
  }
  const int row = blockIdx.x;
  const int base = row * C_ + t * 4;
  float4 xv = *(const float4*)(x + base);
  float4 mv = *(const float4*)(mu + base);
  float4 lv = *(const float4*)(logvar + base);
  float xa[4] = {xv.x, xv.y, xv.z, xv.w};
  float ma[4] = {mv.x, mv.y, mv.z, mv.w};
  float la[4] = {lv.x, lv.y, lv.z, lv.w};
  ushort4 xs, ks, vs;
  ushort_t* xsp = &xs.x; ushort_t* ksp = &ks.x; ushort_t* vsp = &vs.x;
  float l2 = 0.f;
#pragma unroll
  for (int i = 0; i < 4; ++i) {
    float bv  = __expf(la[i]) + 8.0f;   // exp(logvar) + sqrt(HD)
    float inv = 1.0f / bv;
    float kf  = ma[i] * inv;
    float vf  = 8.0f * ma[i] * inv;
    l2 += ma[i] * ma[i] * inv;
    xsp[i] = f2bf(xa[i]); ksp[i] = f2bf(kf); vsp[i] = f2bf(vf);
  }
  *(ushort4*)(xb + base) = xs;
  *(ushort4*)(kp + base) = ks;
  *(ushort4*)(vp + base) = vs;
  l2 += __shfl_xor(l2, 1);  l2 += __shfl_xor(l2, 2);  l2 += __shfl_xor(l2, 4);
  l2 += __shfl_xor(l2, 8);  l2 += __shfl_xor(l2, 16); l2 += __shfl_xor(l2, 32);
  __shared__ float red[4];
  if ((t & 63) == 0) red[t >> 6] = l2;
  __syncthreads();
  if (t == 0) {
    float s = red[0] + red[1] + red[2] + red[3];
    biasv[row] = __logf(alpha[row]) - 0.5f * s;
  }
}

// ---------------------------------------------------------------------------
// Kernel 2: Q/K/V projections — 256x256 tile, BK=32, 512 thr (8 waves 2x4,
// 128x64 out/wave), 4-deep LDS ring (4 x 32KB = 128KB, 1 block/CU).
// Iter kt computes from buf[kt&3] while staging tile kt+3 -> buf[(kt+3)&3];
// end-of-iter vmcnt(8) only waits for loads issued TWO iterations earlier.
// Ring-hazard ledger: buf[(kt+3)&3] was read in iter kt-1; those reads are
// drained (lgkmcnt via MFMA dep) before its end barrier; staging is issued
// after that barrier. Tail: vmcnt 8/4/0 at kt=29/30/31.
//  z=0: Q = xb@wq^T -> Qg ; z=1: K = kp@wk^T -> Kg
//  z=2: V = vp@wv^T -> Vt per-head transposed: Vt[((b*16+h)*64+d)*512 + pos]
// ---------------------------------------------------------------------------
__global__ __launch_bounds__(512, 2) void gemm_qkv_kernel(
    const ushort_t* __restrict__ xb, const ushort_t* __restrict__ kp,
    const ushort_t* __restrict__ vp, const ushort_t* __restrict__ wb,
    ushort_t* __restrict__ Qg, ushort_t* __restrict__ Kg, ushort_t* __restrict__ Vt) {
  __shared__ ushort_t lds[65536];   // 128KB: A ring [4][8192] | B ring at +32768
  const int z = blockIdx.z;
  const ushort_t* Ag = z == 0 ? xb : z == 1 ? kp : vp;
  const ushort_t* Wg = wb + (size_t)z * 1048576;
  const int m0 = blockIdx.x * 256, n0 = blockIdx.y * 256;
  const int t = threadIdx.x, w = t >> 6, lane = t & 63;
  const int wr = w >> 2, wc = w & 3;          // 2x4 wave grid
  const int hi = lane >> 4, r15 = lane & 15;
  const int sa0 = t, sa1 = t + 512;           // staging element ids (row=s&255, chunk=s>>8)

#define STAGE(kt, buf)                                                                   \
  do {                                                                                   \
    const int k0 = (kt) * 32;                                                            \
    gload16(Ag + (size_t)(m0 + (sa0 & 255)) * 1024 + k0 + (sa0 >> 8) * 8,                \
            lds + (buf) * 8192 + (sa0 & ~63) * 8);                                       \
    gload16(Ag + (size_t)(m0 + (sa1 & 255)) * 1024 + k0 + (sa1 >> 8) * 8,                \
            lds + (buf) * 8192 + (sa1 & ~63) * 8);                                       \
    gload16(Wg + (size_t)(n0 + (sa0 & 255)) * 1024 + k0 + (sa0 >> 8) * 8,                \
            lds + 32768 + (buf) * 8192 + (sa0 & ~63) * 8);                               \
    gload16(Wg + (size_t)(n0 + (sa1 & 255)) * 1024 + k0 + (sa1 >> 8) * 8,                \
            lds + 32768 + (buf) * 8192 + (sa1 & ~63) * 8);                               \
  } while (0)

  f32x4 acc[8][4] = {};
  STAGE(0, 0); STAGE(1, 1); STAGE(2, 2);   // 12 instr/wave in flight
  VMCNT8();                                // tile 0 landed (oldest 4 drained)
  SBAR();
  SCHED();

  for (int kt0 = 0; kt0 < 32; kt0 += 4) {
#pragma unroll
    for (int j = 0; j < 4; ++j) {
      const int kt = kt0 + j;               // buf index kt&3 == j (kt0 % 4 == 0)
      if (kt + 3 < 32) STAGE(kt + 3, (j + 3) & 3);
      const ushort_t* Abuf = lds + j * 8192;
      const ushort_t* Bbuf = lds + 32768 + j * 8192;
      bf16x8 bw[4], af[4];
#pragma unroll
      for (int ni = 0; ni < 4; ++ni)
        bw[ni] = *(const bf16x8*)(Bbuf + (hi * 256 + wc * 64 + ni * 16 + r15) * 8);
      // phase A: frag-rows 0..3
#pragma unroll
      for (int mi = 0; mi < 4; ++mi)
        af[mi] = *(const bf16x8*)(Abuf + (hi * 256 + wr * 128 + mi * 16 + r15) * 8);
      __builtin_amdgcn_s_setprio(1);
#pragma unroll
      for (int mi = 0; mi < 4; ++mi)
#pragma unroll
        for (int ni = 0; ni < 4; ++ni)
          acc[mi][ni] = __builtin_amdgcn_mfma_f32_16x16x32_bf16(af[mi], bw[ni], acc[mi][ni], 0, 0, 0);
      __builtin_amdgcn_s_setprio(0);
      SCHED();
      SBAR();                               // pacing (all waves read same buf; no hazard)
      // phase B: frag-rows 4..7
#pragma unroll
      for (int mi = 0; mi < 4; ++mi)
        af[mi] = *(const bf16x8*)(Abuf + (hi * 256 + wr * 128 + (mi + 4) * 16 + r15) * 8);
      __builtin_amdgcn_s_setprio(1);
#pragma unroll
      for (int mi = 0; mi < 4; ++mi)
#pragma unroll
        for (int ni = 0; ni < 4; ++ni)
          acc[mi + 4][ni] = __builtin_amdgcn_mfma_f32_16x16x32_bf16(af[mi], bw[ni], acc[mi + 4][ni], 0, 0, 0);
      __builtin_amdgcn_s_setprio(0);
      SCHED();
      // publish: tile kt+1 (staged at iter kt-2) must be fully landed after this barrier
      if (kt <= 28)      VMCNT8();
      else if (kt == 29) VMCNT4();
      else if (kt == 30) VMCNT0();
      SBAR();
      SCHED();
    }
  }
#undef STAGE

  const int rbase = m0 + wr * 128 + hi * 4;
  const int cbase = n0 + wc * 64 + r15;
  if (z < 2) {
    ushort_t* Out = z == 0 ? Qg : Kg;
#pragma unroll
    for (int mi = 0; mi < 8; ++mi)
#pragma unroll
      for (int ni = 0; ni < 4; ++ni)
#pragma unroll
        for (int q = 0; q < 4; ++q)
          Out[(size_t)(rbase + mi * 16 + q) * 1024 + cbase + ni * 16] = f2bf(acc[mi][ni][q]);
  } else {
#pragma unroll
    for (int mi = 0; mi < 8; ++mi) {
      int m = rbase + mi * 16;
      int b = m >> 9, pos = m & 511;        // pos multiple of 4 -> 8B aligned store
#pragma unroll
      for (int ni = 0; ni < 4; ++ni) {
        int n = cbase + ni * 16;
        int h = n >> 6, d = n & 63;
        ushort4 o;
        o.x = f2bf(acc[mi][ni][0]); o.y = f2bf(acc[mi][ni][1]);
        o.z = f2bf(acc[mi][ni][2]); o.w = f2bf(acc[mi][ni][3]);
        *(ushort4*)(Vt + (size_t)((b * 16 + h) * 64 + d) * 512 + pos) = o;
      }
    }
  }
}

// ---------------------------------------------------------------------------
// GEMM core (128x128, BK=32, 2-phase double-buffered) — used by gemm_out.
// ---------------------------------------------------------------------------
__device__ __forceinline__ void gemm_tile_db(const ushort_t* __restrict__ Ag,
                                             const ushort_t* __restrict__ Wg,
                                             int m0, int n0, f32x4 acc[4][4],
                                             ushort_t* lds) {
  const int t = threadIdx.x;
  const int w = t >> 6, lane = t & 63;
  const int wm = w >> 1, wn = w & 1;
  const int chunk = lane >> 4, r15 = lane & 15;
  const int s0 = t, s1 = t + 256;

#define STAGE_AB(kt, buf)                                                         \
  do {                                                                            \
    const int k0 = (kt) * 32;                                                     \
    gload16(Ag + (size_t)(m0 + (s0 & 127)) * 1024 + k0 + (s0 >> 7) * 8,           \
            lds + (buf) * 4096 + (s0 & ~63) * 8);                                 \
    gload16(Ag + (size_t)(m0 + (s1 & 127)) * 1024 + k0 + (s1 >> 7) * 8,           \
            lds + (buf) * 4096 + (s1 & ~63) * 8);                                 \
    gload16(Wg + (size_t)(n0 + (s0 & 127)) * 1024 + k0 + (s0 >> 7) * 8,           \
            lds + 8192 + (buf) * 4096 + (s0 & ~63) * 8);                          \
    gload16(Wg + (size_t)(n0 + (s1 & 127)) * 1024 + k0 + (s1 >> 7) * 8,           \
            lds + 8192 + (buf) * 4096 + (s1 & ~63) * 8);                          \
  } while (0)

  STAGE_AB(0, 0);
  int cur = 0;
  for (int kt = 0; kt < 32; ++kt) {
    if (kt < 31) { STAGE_AB(kt + 1, cur ^ 1); VMCNT4(); }
    else         { VMCNT0(); }
    SBAR();
    SCHED();
    bf16x8 af[4], bw[4];
#pragma unroll
    for (int mi = 0; mi < 4; ++mi)
      af[mi] = *(const bf16x8*)(lds + cur * 4096 + (chunk * 128 + wm * 64 + mi * 16 + r15) * 8);
#pragma unroll
    for (int ni = 0; ni < 4; ++ni)
      bw[ni] = *(const bf16x8*)(lds + 8192 + cur * 4096 + (chunk * 128 + wn * 64 + ni * 16 + r15) * 8);
#pragma unroll
    for (int mi = 0; mi < 4; ++mi)
#pragma unroll
      for (int ni = 0; ni < 4; ++ni)
        acc[mi][ni] = __builtin_amdgcn_mfma_f32_16x16x32_bf16(af[mi], bw[ni], acc[mi][ni], 0, 0, 0);
    SCHED();
    SBAR();
    SCHED();
    cur ^= 1;
  }
#undef STAGE_AB
}

// ---------------------------------------------------------------------------
// Kernel 3: attention. Block = (b,h) x 64 q-rows; 4 waves, 16 q-rows/wave.
// Full 512-key score row in registers (acc[32] f32x4/lane); register softmax
// via 16-lane shfl; K and V share one 32KB LDS double-buffer; V tile 0
// prefetched under the softmax VALU phase; attn store deferred to the end.
// ---------------------------------------------------------------------------
__global__ __launch_bounds__(256, 2) void attn_kernel(
    const ushort_t* __restrict__ Qg, const ushort_t* __restrict__ Kg,
    const ushort_t* __restrict__ Vt, const float* __restrict__ biasv,
    float* __restrict__ attn_out, ushort_t* __restrict__ Og) {
  __shared__ ushort_t Qt[4096];     // 8KB : [chunk0..7][qrow0..63] x 16B
  __shared__ ushort_t KV[16384];    // 32KB: double buffer, 8192 ushorts each
  __shared__ ushort_t Pl[8192];     // 16KB: per-wave 2048 ushorts
  __shared__ float biasl[512];
  const int bh = blockIdx.x, qt = blockIdx.y;
  const int b = bh >> 4, h = bh & 15;
  const int t = threadIdx.x, w = t >> 6, lane = t & 63;
  const int hi = lane >> 4, r15 = lane & 15;

  {
    float2 bv2 = *(const float2*)(biasv + b * 512 + t * 2);
    biasl[t * 2] = bv2.x; biasl[t * 2 + 1] = bv2.y;
  }
  { // stage Q tile
    int s0 = t, s1 = t + 256;
    gload16(Qg + (size_t)(b * 512 + qt * 64 + (s0 & 63)) * 1024 + h * 64 + (s0 >> 6) * 8,
            Qt + (s0 & ~63) * 8);
    gload16(Qg + (size_t)(b * 512 + qt * 64 + (s1 & 63)) * 1024 + h * 64 + (s1 >> 6) * 8,
            Qt + (s1 & ~63) * 8);
  }

#define STAGE_K(kt, buf)                                                               \
  do {                                                                                 \
    _Pragma("unroll")                                                                  \
    for (int r = 0; r < 4; ++r) {                                                      \
      int s = r * 256 + t; /* chunk=s>>7 (0..7), krow=s&127 */                         \
      gload16(Kg + (size_t)(b * 512 + (kt) * 128 + (s & 127)) * 1024 + h * 64 + (s >> 7) * 8, \
              KV + (buf) * 8192 + (s & ~63) * 8);                                      \
    }                                                                                  \
  } while (0)
#define STAGE_V(kt, buf)                                                               \
  do {                                                                                 \
    _Pragma("unroll")                                                                  \
    for (int r = 0; r < 4; ++r) {                                                      \
      int s = r * 256 + t; /* chunk=s>>6 (0..15), d=s&63 */                            \
      gload16(Vt + (size_t)(bh * 64 + (s & 63)) * 512 + (kt) * 128 + (s >> 6) * 8,     \
              KV + (buf) * 8192 + (s & ~63) * 8);                                      \
    }                                                                                  \
  } while (0)

  STAGE_K(0, 0);
  f32x4 acc[32] = {};
  bf16x8 aq[2];
  int cur = 0;

  // ---- S = Q K^T (2-phase pipelined; last iter prefetches V0) ----
#pragma unroll
  for (int kt = 0; kt < 4; ++kt) {
    if (kt < 3) STAGE_K(kt + 1, cur ^ 1);
    else        STAGE_V(0, cur ^ 1);        // V0 flies through the softmax phase
    VMCNT4();
    SBAR();
    SCHED();
    if (kt == 0) {
#pragma unroll
      for (int ks = 0; ks < 2; ++ks)
        aq[ks] = *(const bf16x8*)(Qt + ((ks * 4 + hi) * 64 + w * 16 + r15) * 8);
    }
    __builtin_amdgcn_s_setprio(1);
#pragma unroll
    for (int mf = 0; mf < 8; ++mf)
#pragma unroll
      for (int ks = 0; ks < 2; ++ks) {
        bf16x8 bk = *(const bf16x8*)(KV + cur * 8192 + ((ks * 4 + hi) * 128 + mf * 16 + r15) * 8);
        acc[kt * 8 + mf] = __builtin_amdgcn_mfma_f32_16x16x32_bf16(aq[ks], bk, acc[kt * 8 + mf], 0, 0, 0);
      }
    __builtin_amdgcn_s_setprio(0);
    SCHED();
    SBAR();
    SCHED();
    cur ^= 1;
  }

  // ---- bias + softmax (registers; row = w*16+hi*4+q, col = f*16+r15) ----
  float mx[4] = {-1e30f, -1e30f, -1e30f, -1e30f};
#pragma unroll
  for (int f = 0; f < 32; ++f) {
    float bv = biasl[f * 16 + r15];
#pragma unroll
    for (int q = 0; q < 4; ++q) {
      acc[f][q] += bv;
      mx[q] = fmaxf(mx[q], acc[f][q]);
    }
  }
#pragma unroll
  for (int q = 0; q < 4; ++q) {
    mx[q] = fmaxf(mx[q], __shfl_xor(mx[q], 1));
    mx[q] = fmaxf(mx[q], __shfl_xor(mx[q], 2));
    mx[q] = fmaxf(mx[q], __shfl_xor(mx[q], 4));
    mx[q] = fmaxf(mx[q], __shfl_xor(mx[q], 8));
  }
  float sm[4] = {0.f, 0.f, 0.f, 0.f};
#pragma unroll
  for (int f = 0; f < 32; ++f)
#pragma unroll
    for (int q = 0; q < 4; ++q) {
      float p = __expf(acc[f][q] - mx[q]);
      acc[f][q] = p;
      sm[q] += p;
    }
#pragma unroll
  for (int q = 0; q < 4; ++q) {
    sm[q] += __shfl_xor(sm[q], 1);
    sm[q] += __shfl_xor(sm[q], 2);
    sm[q] += __shfl_xor(sm[q], 4);
    sm[q] += __shfl_xor(sm[q], 8);
    sm[q] = 1.0f / sm[q];
  }
#pragma unroll
  for (int f = 0; f < 32; ++f)
#pragma unroll
    for (int q = 0; q < 4; ++q)
      acc[f][q] *= sm[q];                   // normalized P, kept for PV + final store

  // ---- O = P V (2-phase; P slab is per-wave private -> no barrier for it) ----
  f32x4 oacc[4] = {};
#pragma unroll
  for (int kt = 0; kt < 4; ++kt) {
    if (kt < 3) STAGE_V(kt + 1, cur ^ 1);
#pragma unroll
    for (int fl = 0; fl < 8; ++fl) {
      int f = kt * 8 + fl;
      int chunkp = fl * 2 + (r15 >> 3);
#pragma unroll
      for (int q = 0; q < 4; ++q)
        Pl[w * 2048 + (chunkp * 16 + hi * 4 + q) * 8 + (lane & 7)] = f2bf(acc[f][q]);
    }
    if (kt < 3) VMCNT4(); else VMCNT0();
    SBAR();
    SCHED();
    __builtin_amdgcn_s_setprio(1);
#pragma unroll
    for (int ks = 0; ks < 4; ++ks) {
      bf16x8 pa = *(const bf16x8*)(Pl + w * 2048 + ((ks * 4 + hi) * 16 + r15) * 8);
#pragma unroll
      for (int df = 0; df < 4; ++df) {
        bf16x8 vb = *(const bf16x8*)(KV + cur * 8192 + ((ks * 4 + hi) * 64 + df * 16 + r15) * 8);
        oacc[df] = __builtin_amdgcn_mfma_f32_16x16x32_bf16(pa, vb, oacc[df], 0, 0, 0);
      }
    }
    __builtin_amdgcn_s_setprio(0);
    SCHED();
    SBAR();
    SCHED();
    cur ^= 1;
  }

  // ---- deferred stores: attn (fp32, mandatory 134MB) then O (bf16) ----
  float* ao = attn_out + ((size_t)bh * 512 + qt * 64 + w * 16 + hi * 4) * 512 + r15;
#pragma unroll
  for (int f = 0; f < 32; ++f)
#pragma unroll
    for (int q = 0; q < 4; ++q)
      ao[(size_t)q * 512 + f * 16] = acc[f][q];

  size_t obase = (size_t)(b * 512 + qt * 64 + w * 16 + hi * 4) * 1024 + h * 64 + r15;
#pragma unroll
  for (int df = 0; df < 4; ++df)
#pragma unroll
    for (int q = 0; q < 4; ++q)
      Og[obase + (size_t)q * 1024 + df * 16] = f2bf(oacc[df][q]);
#undef STAGE_K
#undef STAGE_V
}

// ---------------------------------------------------------------------------
// Kernel 4: out = O @ wp^T + b_p  (fp32 output)
// ---------------------------------------------------------------------------
__global__ __launch_bounds__(256) void gemm_out_kernel(
    const ushort_t* __restrict__ Og, const ushort_t* __restrict__ wb,
    const float* __restrict__ bp, float* __restrict__ out) {
  __shared__ ushort_t lds[16384];
  const int m0 = blockIdx.x * 128, n0 = blockIdx.y * 128;
  f32x4 acc[4][4] = {};
  gemm_tile_db(Og, wb + 3 * 1048576, m0, n0, acc, lds);
  const int t = threadIdx.x, w = t >> 6, lane = t & 63;
  const int wm = w >> 1, wn = w & 1;
  const int rbase = m0 + wm * 64 + (lane >> 4) * 4;
  const int cbase = n0 + wn * 64 + (lane & 15);
#pragma unroll
  for (int mi = 0; mi < 4; ++mi)
#pragma unroll
    for (int ni = 0; ni < 4; ++ni) {
      float bias = bp[cbase + ni * 16];
#pragma unroll
      for (int q = 0; q < 4; ++q)
        out[(size_t)(rbase + mi * 16 + q) * 1024 + cbase + ni * 16] = acc[mi][ni][q] + bias;
    }
}

// ---------------------------------------------------------------------------
// Launch. Workspace layout (bytes):
//   0     xb (8MB) -> reused as Og after QKV   24MB  Qg (8MB)   48MB wb (8MB)
//   8MB   kp (8MB)                             32MB  Kg (8MB)   56MB biasv(16KB)
//   16MB  vp (8MB)                             40MB  Vt (8MB)
// ---------------------------------------------------------------------------
extern "C" void kernel_launch(void* const* d_in, const int* in_sizes, int n_in,
                              void* d_out, int out_size, void* d_ws, size_t ws_size,
                              hipStream_t stream) {
  const float* x      = (const float*)d_in[0];
  const float* mu     = (const float*)d_in[1];
  const float* logvar = (const float*)d_in[2];
  const float* alpha  = (const float*)d_in[3];
  // d_in[4]=pi, d_in[5]=z : unused by the reference
  const float* wq = (const float*)d_in[6];
  const float* wk = (const float*)d_in[7];
  const float* wv = (const float*)d_in[8];
  const float* wp = (const float*)d_in[9];
  const float* bp = (const float*)d_in[10];

  float* out      = (float*)d_out;
  float* attn_out = out + (size_t)M_ * C_;   // second tuple element, fp32

  char* ws = (char*)d_ws;
  ushort_t* xb    = (ushort_t*)(ws);
  ushort_t* kp    = (ushort_t*)(ws + (size_t)8  * 1048576);
  ushort_t* vp    = (ushort_t*)(ws + (size_t)16 * 1048576);
  ushort_t* Qg    = (ushort_t*)(ws + (size_t)24 * 1048576);
  ushort_t* Kg    = (ushort_t*)(ws + (size_t)32 * 1048576);
  ushort_t* Vt    = (ushort_t*)(ws + (size_t)40 * 1048576);
  ushort_t* wb    = (ushort_t*)(ws + (size_t)48 * 1048576);
  float*    biasv = (float*)   (ws + (size_t)56 * 1048576);
  ushort_t* Og    = xb;   // xb dead after QKV GEMMs; attn runs strictly after

  prep_kernel<<<8192, 256, 0, stream>>>(x, mu, logvar, alpha, wq, wk, wv, wp,
                                        xb, kp, vp, biasv, wb);
  gemm_qkv_kernel<<<dim3(16, 4, 3), 512, 0, stream>>>(xb, kp, vp, wb, Qg, Kg, Vt);
  attn_kernel<<<dim3(128, 8), 256, 0, stream>>>(Qg, Kg, Vt, biasv, attn_out, Og);
  gemm_out_kernel<<<dim3(32, 8), 256, 0, stream>>>(Og, wb, bp, out);
}